// Round 3
// baseline (508.061 us; speedup 1.0000x reference)
//
#include <hip/hip_runtime.h>
#include <cstdint>
#include <cstddef>

// Problem constants
#define BB  4
#define NN  32768
#define HH  256
#define SS  64
#define NHH 8
#define HDD 32

typedef __attribute__((ext_vector_type(8))) short s16x8;
typedef __attribute__((ext_vector_type(4))) float f32x4;

__device__ __forceinline__ float dot4(const float4 a, const float4 b) {
    return a.x * b.x + a.y * b.y + a.z * b.z + a.w * b.w;
}

// fp32 -> bf16 (RTNE), returned in low 16 bits
__device__ __forceinline__ unsigned bf16r1(float f) {
    unsigned u = __float_as_uint(f);
    u += 0x7FFFu + ((u >> 16) & 1u);
    return u >> 16;
}
__device__ __forceinline__ unsigned bf16pk(float lo, float hi) {
    return bf16r1(lo) | (bf16r1(hi) << 16);
}

// ---------------------------------------------------------------------------
// K1 fused: scores (MFMA) -> softmax -> W^T into LDS (bf16) + W to global
//           -> pool st += W^T x (MFMA) -> partial
// grid = B*128 blocks, 256 tokens/block, 4 waves (64 tokens each in phase 1,
// 16 slots each in phase 2).
// LDS: wt[64][132] dwords dual-use (sq_w bf16 in phase 1, W^T bf16 pairs
//      afterwards), xt[256][20] dwords for x^T chunks in phase 2. 54.3 KB.
// ---------------------------------------------------------------------------
__global__ __launch_bounds__(256, 2)
void k1_fused(const float* __restrict__ x, const float* __restrict__ sq_w,
              const float* __restrict__ sq_b, unsigned short* __restrict__ Wb,
              float* __restrict__ partial)
{
    __shared__ unsigned wt[64 * 132];  // phase1: sq_w bf16 [s][k/2]; then W^T [s][tokpair]
    __shared__ unsigned xt[256 * 20];  // phase2: x^T chunk [h][tokpair(16)]
    const int t = threadIdx.x;
    const int lane = t & 63, w = t >> 6;
    const int n16 = lane & 15, quad = lane >> 4;
    const int b = blockIdx.x >> 7;
    const int c = blockIdx.x & 127;
    const int tok0 = c * 256;
    const float* xb = x + (size_t)b * NN * HH;

    // stage sq_w into wt as bf16 pairs: [slot][k/2], row stride 132 dwords
    {
        const int r = t >> 2, q = t & 3;
        const float4* src = (const float4*)(sq_w + r * HH + q * 64);
        unsigned* dst = wt + r * 132 + q * 32;
#pragma unroll
        for (int i = 0; i < 16; ++i) {
            float4 v = src[i];
            dst[2 * i]     = bf16pk(v.x, v.y);
            dst[2 * i + 1] = bf16pk(v.z, v.w);
        }
    }
    __syncthreads();

    // ---- phase 1: scores, 64 tokens per wave (4 m-tiles), K=256 ----
    f32x4 acc[4][4];
#pragma unroll
    for (int mt = 0; mt < 4; ++mt)
#pragma unroll
        for (int nt = 0; nt < 4; ++nt) acc[mt][nt] = (f32x4)(0.f);

    for (int kc = 0; kc < 8; ++kc) {
        union { unsigned u[4]; s16x8 s; } af[4];
#pragma unroll
        for (int mt = 0; mt < 4; ++mt) {
            const float* ap = xb + (size_t)(tok0 + w * 64 + mt * 16 + n16) * HH + kc * 32 + quad * 8;
            float4 v0 = ((const float4*)ap)[0];
            float4 v1 = ((const float4*)ap)[1];
            af[mt].u[0] = bf16pk(v0.x, v0.y);
            af[mt].u[1] = bf16pk(v0.z, v0.w);
            af[mt].u[2] = bf16pk(v1.x, v1.y);
            af[mt].u[3] = bf16pk(v1.z, v1.w);
        }
#pragma unroll
        for (int nt = 0; nt < 4; ++nt) {
            union { uint4 u; s16x8 s; } bf;
            bf.u = *((const uint4*)(wt + (nt * 16 + n16) * 132 + kc * 16 + quad * 4));
#pragma unroll
            for (int mt = 0; mt < 4; ++mt)
                acc[mt][nt] = __builtin_amdgcn_mfma_f32_16x16x32_bf16(af[mt].s, bf.s, acc[mt][nt], 0, 0, 0);
        }
    }
    __syncthreads();  // all waves done reading sq_w from wt

    // ---- softmax + write W^T (bf16 pairs) into wt ----
    const float sb0 = sq_b[n16], sb1 = sq_b[16 + n16], sb2 = sq_b[32 + n16], sb3 = sq_b[48 + n16];
#pragma unroll
    for (int mt = 0; mt < 4; ++mt) {
        float p[4][4];  // [r][j]
#pragma unroll
        for (int r = 0; r < 4; ++r) {
            float v0 = acc[mt][0][r] + sb0;
            float v1 = acc[mt][1][r] + sb1;
            float v2 = acc[mt][2][r] + sb2;
            float v3 = acc[mt][3][r] + sb3;
            float m = fmaxf(fmaxf(v0, v1), fmaxf(v2, v3));
#pragma unroll
            for (int msk = 1; msk < 16; msk <<= 1) m = fmaxf(m, __shfl_xor(m, msk));
            float e0 = __expf(v0 - m), e1 = __expf(v1 - m), e2 = __expf(v2 - m), e3 = __expf(v3 - m);
            float s = e0 + e1 + e2 + e3;
#pragma unroll
            for (int msk = 1; msk < 16; msk <<= 1) s += __shfl_xor(s, msk);
            const float inv = 1.f / s;
            p[r][0] = e0 * inv; p[r][1] = e1 * inv; p[r][2] = e2 * inv; p[r][3] = e3 * inv;
        }
        const int tpb = w * 32 + mt * 8 + quad * 2;  // tokpair base for this (mt, quad)
#pragma unroll
        for (int j = 0; j < 4; ++j) {
            wt[(16 * j + n16) * 132 + tpb]     = bf16pk(p[0][j], p[1][j]);
            wt[(16 * j + n16) * 132 + tpb + 1] = bf16pk(p[2][j], p[3][j]);
        }
    }
    __syncthreads();  // W^T complete

    // ---- cooperative coalesced W global write: 256 tokens x 32 dwords ----
    {
        unsigned* wgd = (unsigned*)(Wb + ((size_t)b * NN + tok0) * SS);
#pragma unroll
        for (int i = 0; i < 32; ++i) {
            const int flat = i * 256 + t;
            const int token = flat >> 5, dw = flat & 31;
            const int tp = token >> 1, half = (token & 1) * 16;
            unsigned lo = wt[(2 * dw) * 132 + tp] >> half;
            unsigned hi = wt[(2 * dw + 1) * 132 + tp] >> half;
            wgd[flat] = (lo & 0xFFFFu) | ((hi & 0xFFFFu) << 16);
        }
    }

    // ---- phase 2: pool st[s][h] = sum_t W[t][s] x[t][h], K = 256 tokens ----
    f32x4 pacc[16];
#pragma unroll
    for (int nt = 0; nt < 16; ++nt) pacc[nt] = (f32x4)(0.f);

    const int sp = t & 15, shb = t >> 4;
    for (int kc = 0; kc < 8; ++kc) {
        __syncthreads();  // previous xt reads done
        {   // stage x^T: 32 tokens x 256 h (bf16 pairs)
            const float* r0 = xb + (size_t)(tok0 + kc * 32 + 2 * sp) * HH + shb * 16;
            const float* r1 = r0 + HH;
#pragma unroll
            for (int i = 0; i < 4; ++i) {
                float4 a = ((const float4*)r0)[i];
                float4 bq = ((const float4*)r1)[i];
                unsigned* d = xt + (shb * 16 + i * 4) * 20 + sp;
                d[0]  = bf16pk(a.x, bq.x);
                d[20] = bf16pk(a.y, bq.y);
                d[40] = bf16pk(a.z, bq.z);
                d[60] = bf16pk(a.w, bq.w);
            }
        }
        __syncthreads();
        union { uint4 u; s16x8 s; } av;
        av.u = *((const uint4*)(wt + (w * 16 + n16) * 132 + kc * 16 + quad * 4));
#pragma unroll
        for (int nt = 0; nt < 16; ++nt) {
            union { uint4 u; s16x8 s; } bv;
            bv.u = *((const uint4*)(xt + (nt * 16 + n16) * 20 + quad * 4));
            pacc[nt] = __builtin_amdgcn_mfma_f32_16x16x32_bf16(av.s, bv.s, pacc[nt], 0, 0, 0);
        }
    }
    // write pool partial: slot = w*16 + quad*4 + r, h = nt*16 + n16
    float* pb = partial + (size_t)(b * 128 + c) * SS * HH;
#pragma unroll
    for (int nt = 0; nt < 16; ++nt)
#pragma unroll
        for (int r = 0; r < 4; ++r)
            pb[(size_t)(w * 16 + quad * 4 + r) * HH + nt * 16 + n16] = pacc[nt][r];
}

// ---------------------------------------------------------------------------
// MK_PRE: partial-reduce (128 chunks) + eidetic gate + qkv. grid 64 (slot).
// ---------------------------------------------------------------------------
__global__ __launch_bounds__(256)
void mk_pre(const float* __restrict__ partial, const float* __restrict__ eid_state,
            const float* __restrict__ gw, const float* __restrict__ gb,
            const float* __restrict__ in_w, const float* __restrict__ in_b,
            float* __restrict__ st2g, float* __restrict__ qkv)
{
    __shared__ __align__(16) float s0[4][HH];
    __shared__ __align__(16) float s2[4][HH];
    const int s = blockIdx.x, t = threadIdx.x;

    // reduce partial -> st0 row for slot s, 4 batches (thread: b=t>>6, h=4*(t&63))
    {
        const int bb = t >> 6, hq = t & 63;
        const float* p = partial + ((size_t)(bb * 128) * SS + s) * HH + hq * 4;
        float4 a = make_float4(0.f, 0.f, 0.f, 0.f);
        for (int c = 0; c < 128; ++c) {
            float4 v = *(const float4*)(p + (size_t)c * SS * HH);
            a.x += v.x; a.y += v.y; a.z += v.z; a.w += v.w;
        }
        *(float4*)(&s0[bb][hq * 4]) = a;
    }
    __syncthreads();

    // gate: thread t -> channel t, 4 batches
    float acc[4] = {0.f, 0.f, 0.f, 0.f};
    const float4* wr = (const float4*)(gw + (size_t)t * HH);
    for (int k = 0; k < 64; ++k) {
        float4 wv = wr[k];
#pragma unroll
        for (int bb = 0; bb < 4; ++bb) acc[bb] += dot4(*(const float4*)(&s0[bb][k * 4]), wv);
    }
    const float bias = gb[t];
    const float es = eid_state[s * HH + t];
#pragma unroll
    for (int bb = 0; bb < 4; ++bb) {
        float gate = 1.f / (1.f + __expf(-(acc[bb] + bias)));
        float v = s0[bb][t] + gate * es;
        s2[bb][t] = v;
        st2g[(bb * SS + s) * HH + t] = v;
    }
    __syncthreads();

    // qkv: thread t -> outputs {t, 256+t, 512+t}
#pragma unroll
    for (int third = 0; third < 3; ++third) {
        const int o = third * 256 + t;
        float a4[4] = {0.f, 0.f, 0.f, 0.f};
        const float4* w2 = (const float4*)(in_w + (size_t)o * HH);
        for (int k = 0; k < 64; ++k) {
            float4 wv = w2[k];
#pragma unroll
            for (int bb = 0; bb < 4; ++bb) a4[bb] += dot4(*(const float4*)(&s2[bb][k * 4]), wv);
        }
        const float ib = in_b[o];
#pragma unroll
        for (int bb = 0; bb < 4; ++bb) qkv[(bb * SS + s) * 768 + o] = a4[bb] + ib;
    }
}

// ---------------------------------------------------------------------------
// MK2: multi-head attention over slots; grid 32 = (b, head), 64 threads
// ---------------------------------------------------------------------------
__global__ __launch_bounds__(64)
void mk2_attn(const float* __restrict__ qkv, float* __restrict__ ao)
{
    __shared__ __align__(16) float Ks[SS][36], Vs[SS][36];
    const int b = blockIdx.x >> 3, nh = blockIdx.x & 7;
    const int qi = threadIdx.x;
    const float* base = qkv + (size_t)(b * SS + qi) * 768 + nh * HDD;
    float q[HDD];
#pragma unroll
    for (int d = 0; d < HDD; d += 4) {
        float4 v = *(const float4*)(base + d);
        q[d] = v.x; q[d + 1] = v.y; q[d + 2] = v.z; q[d + 3] = v.w;
        *(float4*)(&Ks[qi][d]) = *(const float4*)(base + 256 + d);
        *(float4*)(&Vs[qi][d]) = *(const float4*)(base + 512 + d);
    }
    __syncthreads();
    float sc[SS];
#pragma unroll
    for (int ki = 0; ki < SS; ++ki) {
        float a = 0.f;
#pragma unroll
        for (int d = 0; d < HDD; ++d) a += q[d] * Ks[ki][d];
        sc[ki] = a * 0.17677669529663687f;
    }
    float m = sc[0];
#pragma unroll
    for (int ki = 1; ki < SS; ++ki) m = fmaxf(m, sc[ki]);
    float ssum = 0.f;
#pragma unroll
    for (int ki = 0; ki < SS; ++ki) { sc[ki] = __expf(sc[ki] - m); ssum += sc[ki]; }
    const float inv = 1.f / ssum;
    float o[HDD];
#pragma unroll
    for (int d = 0; d < HDD; ++d) o[d] = 0.f;
#pragma unroll
    for (int ki = 0; ki < SS; ++ki) {
        const float p = sc[ki] * inv;
#pragma unroll
        for (int d = 0; d < HDD; ++d) o[d] += p * Vs[ki][d];
    }
    float* aob = ao + (size_t)(b * SS + qi) * HH + nh * HDD;
#pragma unroll
    for (int d = 0; d < HDD; d += 4)
        *(float4*)(aob + d) = make_float4(o[d], o[d + 1], o[d + 2], o[d + 3]);
}

__device__ __forceinline__ void block_reduce_2(float& v1, float& v2, float* lds8)
{
#pragma unroll
    for (int m = 32; m; m >>= 1) { v1 += __shfl_xor(v1, m); v2 += __shfl_xor(v2, m); }
    const int w = threadIdx.x >> 6;
    __syncthreads();
    if ((threadIdx.x & 63) == 0) { lds8[w] = v1; lds8[4 + w] = v2; }
    __syncthreads();
    v1 = lds8[0] + lds8[1] + lds8[2] + lds8[3];
    v2 = lds8[4] + lds8[5] + lds8[6] + lds8[7];
}

// ---------------------------------------------------------------------------
// MK_POST: out-proj + LN1 + FFN1 + GELU + FFN2 + LN2 -> st4. grid 64 (slot).
// ---------------------------------------------------------------------------
__global__ __launch_bounds__(256)
void mk_post(const float* __restrict__ ao, const float* __restrict__ out_w,
             const float* __restrict__ out_b, const float* __restrict__ st2g,
             const float* __restrict__ n1g, const float* __restrict__ n1b,
             const float* __restrict__ f1w, const float* __restrict__ f1b,
             const float* __restrict__ f2w, const float* __restrict__ f2b,
             const float* __restrict__ n2g, const float* __restrict__ n2b,
             float* __restrict__ st4)
{
    __shared__ __align__(16) float arow[4][HH];
    __shared__ __align__(16) float s3[4][HH];
    __shared__ __align__(16) float hbuf[4][1024];
    __shared__ float red[8];
    const int s = blockIdx.x, t = threadIdx.x;
#pragma unroll
    for (int bb = 0; bb < 4; ++bb) arow[bb][t] = ao[(bb * SS + s) * HH + t];
    __syncthreads();

    // out-proj + residual + LN1
    float acc[4] = {0.f, 0.f, 0.f, 0.f};
    const float4* wr = (const float4*)(out_w + (size_t)t * HH);
    for (int k = 0; k < 64; ++k) {
        float4 wv = wr[k];
#pragma unroll
        for (int bb = 0; bb < 4; ++bb) acc[bb] += dot4(*(const float4*)(&arow[bb][k * 4]), wv);
    }
    const float ob = out_b[t], g1 = n1g[t], b1 = n1b[t];
#pragma unroll
    for (int bb = 0; bb < 4; ++bb) {
        const float y = st2g[(bb * SS + s) * HH + t] + acc[bb] + ob;
        float s1 = y, sq = y * y;
        block_reduce_2(s1, sq, red);
        const float mu = s1 * (1.f / HH);
        const float var = sq * (1.f / HH) - mu * mu;
        const float r = rsqrtf(var + 1e-5f);
        s3[bb][t] = (y - mu) * r * g1 + b1;
    }
    __syncthreads();

    // FFN1 + exact GELU
#pragma unroll
    for (int q = 0; q < 4; ++q) {
        const int o = q * 256 + t;
        float a4[4] = {0.f, 0.f, 0.f, 0.f};
        const float4* w1 = (const float4*)(f1w + (size_t)o * HH);
        for (int k = 0; k < 64; ++k) {
            float4 wv = w1[k];
#pragma unroll
            for (int bb = 0; bb < 4; ++bb) a4[bb] += dot4(*(const float4*)(&s3[bb][k * 4]), wv);
        }
        const float fb = f1b[o];
#pragma unroll
        for (int bb = 0; bb < 4; ++bb) {
            const float u = a4[bb] + fb;
            hbuf[bb][o] = 0.5f * u * (1.f + erff(u * 0.70710678118654752f));
        }
    }
    __syncthreads();

    // FFN2 + residual + LN2
    float a2[4] = {0.f, 0.f, 0.f, 0.f};
    const float4* w2 = (const float4*)(f2w + (size_t)t * 1024);
    for (int k = 0; k < 256; ++k) {
        float4 wv = w2[k];
#pragma unroll
        for (int bb = 0; bb < 4; ++bb) a2[bb] += dot4(*(const float4*)(&hbuf[bb][k * 4]), wv);
    }
    const float fb2 = f2b[t], g2 = n2g[t], b2 = n2b[t];
#pragma unroll
    for (int bb = 0; bb < 4; ++bb) {
        const float y = s3[bb][t] + a2[bb] + fb2;
        float s1 = y, sq = y * y;
        block_reduce_2(s1, sq, red);
        const float mu = s1 * (1.f / HH);
        const float var = sq * (1.f / HH) - mu * mu;
        const float r = rsqrtf(var + 1e-5f);
        st4[(bb * SS + s) * HH + t] = (y - mu) * r * g2 + b2;
    }
}

// ---------------------------------------------------------------------------
// K3: decode: out = W @ st4 + x via MFMA + LDS-transposed coalesced epilogue.
// grid = B * 512 (64 tokens/block). LDS dual-use: st4^T (36 KB) then
// per-wave transpose scratch (4 rows x 264 dwords per wave).
// ---------------------------------------------------------------------------
__global__ __launch_bounds__(256, 4)
void k3_decode(const unsigned short* __restrict__ Wb, const float* __restrict__ st4,
               const float* __restrict__ x, float* __restrict__ out)
{
    __shared__ union {
        unsigned s4t[256 * 36];   // st4^T bf16 pairs [h][s-pair], stride 36
        float tb[4][4 * 264];     // per-wave epilogue transpose: 4 rows x 264
    } u;
    const int t = threadIdx.x;
    const int lane = t & 63, w = t >> 6;
    const int n16 = lane & 15, quad = lane >> 4;
    const int b = blockIdx.x >> 9;
    const int c = blockIdx.x & 511;
    const int tok0 = c * 64;
    {
        const int sp = t & 31, hb = t >> 5;
        const float* r0 = st4 + (size_t)(b * SS + 2 * sp) * HH + hb * 32;
        const float* r1 = r0 + HH;
#pragma unroll
        for (int i = 0; i < 8; ++i) {
            float4 a = ((const float4*)r0)[i];
            float4 bq = ((const float4*)r1)[i];
            unsigned* d = u.s4t + (hb * 32 + i * 4) * 36 + sp;
            d[0]   = bf16pk(a.x, bq.x);
            d[36]  = bf16pk(a.y, bq.y);
            d[72]  = bf16pk(a.z, bq.z);
            d[108] = bf16pk(a.w, bq.w);
        }
    }
    f32x4 acc[16];
#pragma unroll
    for (int nt = 0; nt < 16; ++nt) acc[nt] = (f32x4)(0.f);
    __syncthreads();

    const unsigned short* wrow = Wb + ((size_t)b * NN + tok0 + w * 16 + n16) * SS;
#pragma unroll
    for (int ks = 0; ks < 2; ++ks) {
        union { uint4 u4; s16x8 s; } av;
        av.u4 = *((const uint4*)(wrow + ks * 32 + quad * 8));
#pragma unroll
        for (int nt = 0; nt < 16; ++nt) {
            union { uint4 u4; s16x8 s; } bv;
            bv.u4 = *((const uint4*)(u.s4t + (nt * 16 + n16) * 36 + ks * 16 + quad * 4));
            acc[nt] = __builtin_amdgcn_mfma_f32_16x16x32_bf16(av.s, bv.s, acc[nt], 0, 0, 0);
        }
    }
    __syncthreads();  // done reading s4t; reuse as transpose scratch

    float* tb = u.tb[w];
    const size_t gbase = (size_t)b * NN + tok0 + w * 16;
#pragma unroll
    for (int r = 0; r < 4; ++r) {
        // rows quad*4+r (fixed r): lane deposits its 16 C-elements
#pragma unroll
        for (int nt = 0; nt < 16; ++nt)
            tb[quad * 264 + nt * 16 + n16] = acc[nt][r];
        __syncthreads();
#pragma unroll
        for (int q = 0; q < 4; ++q) {
            const size_t go = (gbase + q * 4 + r) * HH + lane * 4;
            float4 v = *(const float4*)(tb + q * 264 + lane * 4);
            float4 xv = *(const float4*)(x + go);
            v.x += xv.x; v.y += xv.y; v.z += xv.z; v.w += xv.w;
            *(float4*)(out + go) = v;
        }
        __syncthreads();
    }
}

// ---------------------------------------------------------------------------
extern "C" void kernel_launch(void* const* d_in, const int* in_sizes, int n_in,
                              void* d_out, int out_size, void* d_ws, size_t ws_size,
                              hipStream_t stream)
{
    const float* x         = (const float*)d_in[0];
    const float* sq_w      = (const float*)d_in[1];
    const float* sq_b      = (const float*)d_in[2];
    const float* eid_state = (const float*)d_in[3];
    const float* eid_gw    = (const float*)d_in[4];
    const float* eid_gb    = (const float*)d_in[5];
    const float* in_w      = (const float*)d_in[6];
    const float* in_b      = (const float*)d_in[7];
    const float* out_w     = (const float*)d_in[8];
    const float* out_b     = (const float*)d_in[9];
    const float* n1_g      = (const float*)d_in[10];
    const float* n1_b      = (const float*)d_in[11];
    const float* n2_g      = (const float*)d_in[12];
    const float* n2_b      = (const float*)d_in[13];
    const float* f1_w      = (const float*)d_in[14];
    const float* f1_b      = (const float*)d_in[15];
    const float* f2_w      = (const float*)d_in[16];
    const float* f2_b      = (const float*)d_in[17];

    float* ws = (float*)d_ws;
    unsigned short* Wb = (unsigned short*)ws;      // [B][N][S] bf16 = 4194304 floats
    float* partial = ws + 4194304;                 // [B][128][S][H] 8388608
    float* st2     = partial + 8388608;            // [B][S][H] 65536
    float* qkv     = st2 + 65536;                  // [B][S][768] 196608
    float* ao      = qkv + 196608;                 // [B][S][H] 65536
    float* st4     = ao + 65536;                   // [B][S][H] 65536
    float* out     = (float*)d_out;

    hipLaunchKernelGGL(k1_fused, dim3(BB * 128), dim3(256), 0, stream,
                       x, sq_w, sq_b, Wb, partial);
    hipLaunchKernelGGL(mk_pre, dim3(SS), dim3(256), 0, stream,
                       partial, eid_state, eid_gw, eid_gb, in_w, in_b, st2, qkv);
    hipLaunchKernelGGL(mk2_attn, dim3(BB * NHH), dim3(64), 0, stream, qkv, ao);
    hipLaunchKernelGGL(mk_post, dim3(SS), dim3(256), 0, stream,
                       ao, out_w, out_b, st2, n1_g, n1_b, f1_w, f1_b,
                       f2_w, f2_b, n2_g, n2_b, st4);
    hipLaunchKernelGGL(k3_decode, dim3(BB * 512), dim3(256), 0, stream,
                       Wb, st4, x, out);
}